// Round 6
// baseline (876.517 us; speedup 1.0000x reference)
//
#include <hip/hip_runtime.h>
#include <hip/hip_bf16.h>
#include <cstdint>
#include <cstddef>
#include <cmath>

#define F_IN 256
#define HDIM 128
#define CCLS 40
#define NBMAX 1024   // max buckets (n<=65536); n=50000 -> 782

__device__ inline unsigned pkbf(float a, float b) {
  __hip_bfloat162 h = __float22bfloat162_rn(make_float2(a, b));
  unsigned u;
  __builtin_memcpy(&u, &h, 4);
  return u;
}

// ---------------- row L2 norm: one wave per row ----------------
__global__ __launch_bounds__(256) void norm_kernel(const float* __restrict__ x,
                                                   float* __restrict__ inv_norm, int n) {
  int wv = threadIdx.x >> 6, l = threadIdx.x & 63;
  int row = blockIdx.x * 4 + wv;
  if (row >= n) return;
  float4 v = *(const float4*)(x + (size_t)row * F_IN + l * 4);
  float s = v.x * v.x + v.y * v.y + v.z * v.z + v.w * v.w;
#pragma unroll
  for (int off = 32; off; off >>= 1) s += __shfl_xor(s, off, 64);
  if (l == 0) inv_norm[row] = 1.0f / fmaxf(sqrtf(s), 1e-12f);
}

// ---------------- bucket histogram (bucket = dst>>6), int4 loads ----------------
__global__ __launch_bounds__(256) void bucket_hist(const int* __restrict__ dst,
                                                   int* __restrict__ gcount, int e, int nb) {
  __shared__ int h[NBMAX];
  for (int i = threadIdx.x; i < nb; i += 256) h[i] = 0;
  __syncthreads();
  int b4 = blockIdx.x * 1024;  // int4 units; 4096 edges per block
#pragma unroll
  for (int k = 0; k < 4; ++k) {
    int gi = b4 + k * 256 + threadIdx.x;
    int e0 = gi * 4;
    int4 d = make_int4(-1, -1, -1, -1);
    if (e0 + 3 < e) d = ((const int4*)dst)[gi];
    else if (e0 < e) {
      d.x = dst[e0];
      if (e0 + 1 < e) d.y = dst[e0 + 1];
      if (e0 + 2 < e) d.z = dst[e0 + 2];
    }
    if (d.x >= 0) atomicAdd(&h[d.x >> 6], 1);
    if (d.y >= 0) atomicAdd(&h[d.y >> 6], 1);
    if (d.z >= 0) atomicAdd(&h[d.z >> 6], 1);
    if (d.w >= 0) atomicAdd(&h[d.w >> 6], 1);
  }
  __syncthreads();
  for (int i = threadIdx.x; i < nb; i += 256)
    if (h[i]) atomicAdd(&gcount[i], h[i]);
}

// ---------------- exclusive scan of bucket counts (1 block) ----------------
__global__ __launch_bounds__(256) void bucket_scan(const int* __restrict__ gcount,
                                                   int* __restrict__ boff,
                                                   int* __restrict__ gcursor,
                                                   int* __restrict__ row_off,
                                                   int nb, int n) {
  __shared__ int part[256];
  int t = threadIdx.x;
  int v[4];
  int s = 0;
#pragma unroll
  for (int k = 0; k < 4; ++k) {
    int i = t * 4 + k;
    v[k] = (i < nb) ? gcount[i] : 0;
    s += v[k];
  }
  part[t] = s;
  __syncthreads();
  for (int off = 1; off < 256; off <<= 1) {
    int x = part[t];
    if (t >= off) x += part[t - off];
    __syncthreads();
    part[t] = x;
    __syncthreads();
  }
  int run = (t == 0) ? 0 : part[t - 1];
#pragma unroll
  for (int k = 0; k < 4; ++k) {
    int i = t * 4 + k;
    if (i < nb) { boff[i] = run; gcursor[i] = run; }
    run += v[k];
  }
  if (t == 255) { boff[nb] = part[255]; row_off[n] = part[255]; }
}

// ---------------- block-multisplit scatter, int4/float4 loads ----------------
// edge record: meta = (dst&63)<<26 | src ; w as bits
#define EPB 8192
__global__ __launch_bounds__(256) void bucket_scatter(const int* __restrict__ src,
                                                      const int* __restrict__ dst,
                                                      const float* __restrict__ w,
                                                      int* __restrict__ gcursor,
                                                      uint2* __restrict__ ews, int e, int nb) {
  __shared__ int hist[NBMAX];
  __shared__ int gbase[NBMAX];
  __shared__ int lcur[NBMAX];
  const int t = threadIdx.x;
  for (int i = t; i < nb; i += 256) { hist[i] = 0; lcur[i] = 0; }
  __syncthreads();
  const int b4 = blockIdx.x * 2048;  // int4 units; 8192 edges per block
  int4 dv[8];
#pragma unroll
  for (int k = 0; k < 8; ++k) {
    int gi = b4 + k * 256 + t;
    int e0 = gi * 4;
    int4 d = make_int4(-1, -1, -1, -1);
    if (e0 + 3 < e) d = ((const int4*)dst)[gi];
    else if (e0 < e) {
      d.x = dst[e0];
      if (e0 + 1 < e) d.y = dst[e0 + 1];
      if (e0 + 2 < e) d.z = dst[e0 + 2];
    }
    dv[k] = d;
    if (d.x >= 0) atomicAdd(&hist[d.x >> 6], 1);
    if (d.y >= 0) atomicAdd(&hist[d.y >> 6], 1);
    if (d.z >= 0) atomicAdd(&hist[d.z >> 6], 1);
    if (d.w >= 0) atomicAdd(&hist[d.w >> 6], 1);
  }
  __syncthreads();
  for (int i = t; i < nb; i += 256) {
    int c = hist[i];
    gbase[i] = c ? atomicAdd(&gcursor[i], c) : 0;
  }
  __syncthreads();
#pragma unroll
  for (int k = 0; k < 8; ++k) {
    int gi = b4 + k * 256 + t;
    int e0 = gi * 4;
    if (e0 >= e) continue;
    int4 s4 = make_int4(0, 0, 0, 0);
    float4 w4 = make_float4(0.f, 0.f, 0.f, 0.f);
    if (e0 + 3 < e) { s4 = ((const int4*)src)[gi]; w4 = ((const float4*)w)[gi]; }
    else {
      s4.x = src[e0]; w4.x = w[e0];
      if (e0 + 1 < e) { s4.y = src[e0 + 1]; w4.y = w[e0 + 1]; }
      if (e0 + 2 < e) { s4.z = src[e0 + 2]; w4.z = w[e0 + 2]; }
    }
    int4 d = dv[k];
    if (d.x >= 0) { int bb = d.x >> 6; int r = atomicAdd(&lcur[bb], 1);
      ews[gbase[bb] + r] = make_uint2(((unsigned)(d.x & 63) << 26) | (unsigned)s4.x, __float_as_uint(w4.x)); }
    if (d.y >= 0) { int bb = d.y >> 6; int r = atomicAdd(&lcur[bb], 1);
      ews[gbase[bb] + r] = make_uint2(((unsigned)(d.y & 63) << 26) | (unsigned)s4.y, __float_as_uint(w4.y)); }
    if (d.z >= 0) { int bb = d.z >> 6; int r = atomicAdd(&lcur[bb], 1);
      ews[gbase[bb] + r] = make_uint2(((unsigned)(d.z & 63) << 26) | (unsigned)s4.z, __float_as_uint(w4.z)); }
    if (d.w >= 0) { int bb = d.w >> 6; int r = atomicAdd(&lcur[bb], 1);
      ews[gbase[bb] + r] = make_uint2(((unsigned)(d.w & 63) << 26) | (unsigned)s4.w, __float_as_uint(w4.w)); }
  }
}

// ---------------- per-bucket dst-sort: bucket-grouped -> dst-sorted CSR ----------------
__global__ __launch_bounds__(256) void bucket_sort(const uint2* __restrict__ ews,
                                                   const int* __restrict__ boff,
                                                   uint2* __restrict__ ews2,
                                                   int* __restrict__ row_off,
                                                   int n) {
  __shared__ int cnt64[64];
  __shared__ int cur[64];
  const int t = threadIdx.x;
  const int b = blockIdx.x;
  const int e0 = boff[b], e1 = boff[b + 1];
  if (t < 64) cnt64[t] = 0;
  __syncthreads();
  for (int i = e0 + t; i < e1; i += 256) atomicAdd(&cnt64[(unsigned)ews[i].x >> 26], 1);
  __syncthreads();
  if (t == 0) {
    int run = 0;
    for (int d = 0; d < 64; ++d) {
      int c = cnt64[d];
      cur[d] = run;
      run += c;
    }
  }
  __syncthreads();
  if (t < 64) {
    int node = b * 64 + t;
    if (node < n) row_off[node] = e0 + cur[t];
  }
  __syncthreads();
  for (int i = e0 + t; i < e1; i += 256) {
    uint2 p = ews[i];
    int d = (unsigned)p.x >> 26;
    int pos = e0 + atomicAdd(&cur[d], 1);
    ews2[pos] = make_uint2(p.x & 0x3FFFFFFu, p.y);
  }
}

// ---------------- SPMM v3: bf16 gather, wave/node, 4 edges per VMEM ----------------
__global__ __launch_bounds__(256) void spmm_bf16(const unsigned short* __restrict__ xin,
                                                 const uint2* __restrict__ ews,
                                                 const int* __restrict__ row_off,
                                                 const float* __restrict__ bias,
                                                 float* __restrict__ outp, int n,
                                                 int do_relu) {
  const int t = threadIdx.x;
  const int l = t & 63;
  const int node = blockIdx.x * 4 + (t >> 6);  // one wave per node
  if (node >= n) return;
  const int ue0 = __builtin_amdgcn_readfirstlane(row_off[node]);
  const int ue1 = __builtin_amdgcn_readfirstlane(row_off[node + 1]);
  const int cnt = ue1 - ue0;
  const uint2* ep = ews + ue0;   // wave-uniform -> scalar loads
  const int q = l >> 4;          // which of 4 edges this lane serves
  const int fo = (l & 15) * 8;   // feature offset (elements), 8 bf16 = 16 B per lane
  float acc[8];
#pragma unroll
  for (int j = 0; j < 8; ++j) acc[j] = 0.f;

  for (int k = 0; k < cnt; k += 16) {
    uint2 er[16];
#pragma unroll
    for (int i = 0; i < 16; ++i) er[i] = ep[k + i];   // pad (16 recs) covers overrun
#pragma unroll
    for (int g = 0; g < 4; ++g) {
      uint2 ed = (q == 0) ? er[g * 4 + 0]
               : (q == 1) ? er[g * 4 + 1]
               : (q == 2) ? er[g * 4 + 2]
                          : er[g * 4 + 3];
      const bool ok = (k + g * 4 + q) < cnt;
      const unsigned sv = ok ? ed.x : 0u;
      const float wt = ok ? __uint_as_float(ed.y) : 0.f;
      const uint4 xv = *(const uint4*)(xin + (size_t)sv * HDIM + fo);
      acc[0] = fmaf(wt, __uint_as_float(xv.x << 16), acc[0]);
      acc[1] = fmaf(wt, __uint_as_float(xv.x & 0xFFFF0000u), acc[1]);
      acc[2] = fmaf(wt, __uint_as_float(xv.y << 16), acc[2]);
      acc[3] = fmaf(wt, __uint_as_float(xv.y & 0xFFFF0000u), acc[3]);
      acc[4] = fmaf(wt, __uint_as_float(xv.z << 16), acc[4]);
      acc[5] = fmaf(wt, __uint_as_float(xv.z & 0xFFFF0000u), acc[5]);
      acc[6] = fmaf(wt, __uint_as_float(xv.w << 16), acc[6]);
      acc[7] = fmaf(wt, __uint_as_float(xv.w & 0xFFFF0000u), acc[7]);
    }
  }
#pragma unroll
  for (int j = 0; j < 8; ++j) {
    acc[j] += __shfl_xor(acc[j], 16, 64);
    acc[j] += __shfl_xor(acc[j], 32, 64);
  }
  if (l < 16) {
    float4 b0 = *(const float4*)(bias + fo);
    float4 b1 = *(const float4*)(bias + fo + 4);
    float4 r0 = make_float4(acc[0] + b0.x, acc[1] + b0.y, acc[2] + b0.z, acc[3] + b0.w);
    float4 r1 = make_float4(acc[4] + b1.x, acc[5] + b1.y, acc[6] + b1.z, acc[7] + b1.w);
    if (do_relu) {
      r0.x = fmaxf(r0.x, 0.f); r0.y = fmaxf(r0.y, 0.f);
      r0.z = fmaxf(r0.z, 0.f); r0.w = fmaxf(r0.w, 0.f);
      r1.x = fmaxf(r1.x, 0.f); r1.y = fmaxf(r1.y, 0.f);
      r1.z = fmaxf(r1.z, 0.f); r1.w = fmaxf(r1.w, 0.f);
    }
    *(float4*)(outp + (size_t)node * HDIM + fo) = r0;
    *(float4*)(outp + (size_t)node * HDIM + fo + 4) = r1;
  }
}

// ---------------- fp32 tiled GEMM, bf16 output: C[M][128] = (scale.A)[M][K] @ W[K][128] ----------------
template <int K, bool SCALE>
__global__ __launch_bounds__(256) void gemm_kernel(const float* __restrict__ A,
                                                   const float* __restrict__ W,
                                                   const float* __restrict__ scale,
                                                   unsigned short* __restrict__ C, int M) {
  __shared__ float AsT[32][64];   // transposed: AsT[k][row] -> b128 fragment reads
  __shared__ float Bs[32][128];
  const int t = threadIdx.x;
  const int tx = t & 15, ty = t >> 4;
  const int m0 = blockIdx.x * 64;
  float acc[4][8];
#pragma unroll
  for (int r = 0; r < 4; ++r)
#pragma unroll
    for (int c = 0; c < 8; ++c) acc[r][c] = 0.f;

  for (int k0 = 0; k0 < K; k0 += 32) {
#pragma unroll
    for (int j = 0; j < 2; ++j) {
      int i = t + j * 256;
      int row = i >> 3, q = i & 7;
      int gr = m0 + row;
      float4 v = make_float4(0.f, 0.f, 0.f, 0.f);
      if (gr < M) {
        v = *(const float4*)(A + (size_t)gr * K + k0 + q * 4);
        if (SCALE) {
          float sc = scale[gr];
          v.x *= sc; v.y *= sc; v.z *= sc; v.w *= sc;
        }
      }
      AsT[q * 4 + 0][row] = v.x;
      AsT[q * 4 + 1][row] = v.y;
      AsT[q * 4 + 2][row] = v.z;
      AsT[q * 4 + 3][row] = v.w;
    }
#pragma unroll
    for (int j = 0; j < 4; ++j) {
      int i = t + j * 256;
      int kr = i >> 5, n4 = i & 31;
      *(float4*)&Bs[kr][n4 * 4] = *(const float4*)(W + (size_t)(k0 + kr) * HDIM + n4 * 4);
    }
    __syncthreads();
#pragma unroll
    for (int kr = 0; kr < 32; ++kr) {
      const float4 a4 = *(const float4*)&AsT[kr][ty * 4];
      float4 b0 = *(const float4*)&Bs[kr][tx * 8];
      float4 b1 = *(const float4*)&Bs[kr][tx * 8 + 4];
      float a[4] = {a4.x, a4.y, a4.z, a4.w};
      float bb[8] = {b0.x, b0.y, b0.z, b0.w, b1.x, b1.y, b1.z, b1.w};
#pragma unroll
      for (int r = 0; r < 4; ++r)
#pragma unroll
        for (int c = 0; c < 8; ++c) acc[r][c] = fmaf(a[r], bb[c], acc[r][c]);
    }
    __syncthreads();
  }
#pragma unroll
  for (int r = 0; r < 4; ++r) {
    int gr = m0 + ty * 4 + r;
    if (gr < M) {
      uint4 o;
      o.x = pkbf(acc[r][0], acc[r][1]);
      o.y = pkbf(acc[r][2], acc[r][3]);
      o.z = pkbf(acc[r][4], acc[r][5]);
      o.w = pkbf(acc[r][6], acc[r][7]);
      *(uint4*)(C + (size_t)gr * HDIM + tx * 8) = o;
    }
  }
}

// ---------------- fold label-emb weights: Wc = We @ Wf_top, bc = be @ Wf_top + bf ----------------
__global__ __launch_bounds__(256) void wc_kernel(const float* __restrict__ We,
                                                 const float* __restrict__ be,
                                                 const float* __restrict__ Wf,
                                                 const float* __restrict__ bf,
                                                 float* __restrict__ Wc,
                                                 float* __restrict__ bc) {
  int t = threadIdx.x;
  for (int i = t; i < CCLS * CCLS; i += 256) {
    int c = i / CCLS, j = i % CCLS;
    float s = 0.f;
    for (int f = 0; f < HDIM; ++f) s += We[c * HDIM + f] * Wf[f * CCLS + j];
    Wc[i] = s;
  }
  if (t < CCLS) {
    float s = bf[t];
    for (int f = 0; f < HDIM; ++f) s += be[f] * Wf[f * CCLS + t];
    bc[t] = s;
  }
}

// ---------------- head v3: lane-per-node, acc[40] in regs, W as LDS broadcasts ----------------
// sW layout: rows 0..39 = Wc (y part), rows 40..167 = Wf[128:256] (h2 part), row 168 = bc.
__global__ __launch_bounds__(64) void head_kernel(const float* __restrict__ y,
                                                  const float* __restrict__ h2,
                                                  const float* __restrict__ Wc,
                                                  const float* __restrict__ bc,
                                                  const float* __restrict__ Wf,
                                                  float* __restrict__ out, int n) {
  __shared__ float sW[169 * CCLS];
  const int t = threadIdx.x;
  for (int i = t; i < 400; i += 64) ((float4*)sW)[i] = ((const float4*)Wc)[i];
  for (int i = t; i < 1280; i += 64)
    ((float4*)(sW + CCLS * CCLS))[i] = ((const float4*)(Wf + HDIM * CCLS))[i];
  if (t < 10) ((float4*)(sW + 168 * CCLS))[t] = ((const float4*)bc)[t];
  __syncthreads();

  const int node = blockIdx.x * 64 + t;
  const int nc = node < n ? node : n - 1;
  const float* zy = y + (size_t)nc * CCLS;
  const float* zh = h2 + (size_t)nc * HDIM;

  float acc[40];
#pragma unroll
  for (int cq = 0; cq < 10; ++cq) {
    float4 b4 = *(const float4*)&sW[168 * CCLS + cq * 4];
    acc[cq * 4 + 0] = b4.x; acc[cq * 4 + 1] = b4.y;
    acc[cq * 4 + 2] = b4.z; acc[cq * 4 + 3] = b4.w;
  }

#pragma unroll 2
  for (int kc = 0; kc < 10; ++kc) {      // y part: K = 40
    float4 zv = *(const float4*)(zy + kc * 4);
    float zj[4] = {zv.x, zv.y, zv.z, zv.w};
#pragma unroll
    for (int j = 0; j < 4; ++j) {
      const float* wr = sW + (kc * 4 + j) * CCLS;
#pragma unroll
      for (int cq = 0; cq < 10; ++cq) {
        float4 w4 = *(const float4*)(wr + cq * 4);
        acc[cq * 4 + 0] = fmaf(zj[j], w4.x, acc[cq * 4 + 0]);
        acc[cq * 4 + 1] = fmaf(zj[j], w4.y, acc[cq * 4 + 1]);
        acc[cq * 4 + 2] = fmaf(zj[j], w4.z, acc[cq * 4 + 2]);
        acc[cq * 4 + 3] = fmaf(zj[j], w4.w, acc[cq * 4 + 3]);
      }
    }
  }
#pragma unroll 2
  for (int kc = 0; kc < 32; ++kc) {      // h2 part: K = 128
    float4 zv = *(const float4*)(zh + kc * 4);
    float zj[4] = {zv.x, zv.y, zv.z, zv.w};
#pragma unroll
    for (int j = 0; j < 4; ++j) {
      const float* wr = sW + (40 + kc * 4 + j) * CCLS;
#pragma unroll
      for (int cq = 0; cq < 10; ++cq) {
        float4 w4 = *(const float4*)(wr + cq * 4);
        acc[cq * 4 + 0] = fmaf(zj[j], w4.x, acc[cq * 4 + 0]);
        acc[cq * 4 + 1] = fmaf(zj[j], w4.y, acc[cq * 4 + 1]);
        acc[cq * 4 + 2] = fmaf(zj[j], w4.z, acc[cq * 4 + 2]);
        acc[cq * 4 + 3] = fmaf(zj[j], w4.w, acc[cq * 4 + 3]);
      }
    }
  }

  // in-register softmax over 40 logits
  float m = acc[0];
#pragma unroll
  for (int c = 1; c < 40; ++c) m = fmaxf(m, acc[c]);
  float sum = 0.f;
#pragma unroll
  for (int c = 0; c < 40; ++c) { acc[c] = __expf(acc[c] - m); sum += acc[c]; }
  float inv = 1.0f / sum;
  if (node < n) {
    float* op = out + (size_t)node * CCLS;
#pragma unroll
    for (int cq = 0; cq < 10; ++cq) {
      float4 o = make_float4(acc[cq * 4 + 0] * inv, acc[cq * 4 + 1] * inv,
                             acc[cq * 4 + 2] * inv, acc[cq * 4 + 3] * inv);
      *(float4*)(op + cq * 4) = o;
    }
  }
}

extern "C" void kernel_launch(void* const* d_in, const int* in_sizes, int n_in,
                              void* d_out, int out_size, void* d_ws, size_t ws_size,
                              hipStream_t stream) {
  (void)n_in; (void)out_size; (void)ws_size;
  const float* features = (const float*)d_in[0];
  const int*   src      = (const int*)d_in[1];
  const int*   dst      = (const int*)d_in[2];
  const float* ew       = (const float*)d_in[3];
  const float* y        = (const float*)d_in[4];
  const float* W1       = (const float*)d_in[5];
  const float* b1       = (const float*)d_in[6];
  const float* W2       = (const float*)d_in[7];
  const float* b2       = (const float*)d_in[8];
  const float* We       = (const float*)d_in[9];
  const float* be       = (const float*)d_in[10];
  const float* Wf       = (const float*)d_in[11];
  const float* bf       = (const float*)d_in[12];
  float* out = (float*)d_out;

  const int n = in_sizes[0] / F_IN;   // 50000
  const int e = in_sizes[1];          // 1600000
  const int nb = (n + 63) >> 6;       // 782 buckets

  char* w = (char*)d_ws;
  auto take = [&](size_t bytes) {
    char* p = w;
    w += (bytes + 255) & ~(size_t)255;
    return p;
  };
  float* inv_norm = (float*)take((size_t)n * 4);
  int*   gcount   = (int*)take((size_t)nb * 4);
  int*   boff     = (int*)take((size_t)(nb + 1) * 4);
  int*   gcursor  = (int*)take((size_t)nb * 4);
  int*   row_off  = (int*)take((size_t)(n + 1) * 4);
  uint2* ews      = (uint2*)take((size_t)e * 8);
  uint2* ews2     = (uint2*)take((size_t)(e + 16) * 8);
  unsigned short* bufH = (unsigned short*)take((size_t)n * HDIM * 2);  // bf16 gemm out
  float* bufS     = (float*)take((size_t)n * HDIM * 4);                 // fp32 spmm out
  float* Wc       = (float*)take(CCLS * CCLS * 4);
  float* bc       = (float*)take(CCLS * 4);

  hipMemsetAsync(gcount, 0, (size_t)nb * 4, stream);
  norm_kernel<<<(n + 3) / 4, 256, 0, stream>>>(features, inv_norm, n);
  bucket_hist<<<(e + 4095) / 4096, 256, 0, stream>>>(dst, gcount, e, nb);
  bucket_scan<<<1, 256, 0, stream>>>(gcount, boff, gcursor, row_off, nb, n);
  bucket_scatter<<<(e + EPB - 1) / EPB, 256, 0, stream>>>(src, dst, ew, gcursor, ews, e, nb);
  bucket_sort<<<nb, 256, 0, stream>>>(ews, boff, ews2, row_off, n);
  wc_kernel<<<1, 256, 0, stream>>>(We, be, Wf, bf, Wc, bc);

  gemm_kernel<F_IN, true><<<(n + 63) / 64, 256, 0, stream>>>(features, W1, inv_norm, bufH, n);
  spmm_bf16<<<(n + 3) / 4, 256, 0, stream>>>(bufH, ews2, row_off, b1, bufS, n, 1);
  gemm_kernel<HDIM, false><<<(n + 63) / 64, 256, 0, stream>>>(bufS, W2, nullptr, bufH, n);
  spmm_bf16<<<(n + 3) / 4, 256, 0, stream>>>(bufH, ews2, row_off, b2, bufS, n, 0);
  head_kernel<<<(n + 63) / 64, 64, 0, stream>>>(y, bufS, Wc, bc, Wf, out, n);
}

// Round 7
// 444.852 us; speedup vs baseline: 1.9704x; 1.9704x over previous
//
#include <hip/hip_runtime.h>
#include <hip/hip_bf16.h>
#include <cstdint>
#include <cstddef>
#include <cmath>

#define F_IN 256
#define HDIM 128
#define CCLS 40
#define NBMAX 1024   // max buckets (n<=65536); n=50000 -> 782

__device__ inline unsigned pkbf(float a, float b) {
  __hip_bfloat162 h = __float22bfloat162_rn(make_float2(a, b));
  unsigned u;
  __builtin_memcpy(&u, &h, 4);
  return u;
}

// ---------------- row L2 norm: one wave per row ----------------
__global__ __launch_bounds__(256) void norm_kernel(const float* __restrict__ x,
                                                   float* __restrict__ inv_norm, int n) {
  int wv = threadIdx.x >> 6, l = threadIdx.x & 63;
  int row = blockIdx.x * 4 + wv;
  if (row >= n) return;
  float4 v = *(const float4*)(x + (size_t)row * F_IN + l * 4);
  float s = v.x * v.x + v.y * v.y + v.z * v.z + v.w * v.w;
#pragma unroll
  for (int off = 32; off; off >>= 1) s += __shfl_xor(s, off, 64);
  if (l == 0) inv_norm[row] = 1.0f / fmaxf(sqrtf(s), 1e-12f);
}

// ---------------- bucket histogram (bucket = dst>>6), int4 loads ----------------
__global__ __launch_bounds__(256) void bucket_hist(const int* __restrict__ dst,
                                                   int* __restrict__ gcount, int e, int nb) {
  __shared__ int h[NBMAX];
  for (int i = threadIdx.x; i < nb; i += 256) h[i] = 0;
  __syncthreads();
  int b4 = blockIdx.x * 1024;  // int4 units; 4096 edges per block
#pragma unroll
  for (int k = 0; k < 4; ++k) {
    int gi = b4 + k * 256 + threadIdx.x;
    int e0 = gi * 4;
    int4 d = make_int4(-1, -1, -1, -1);
    if (e0 + 3 < e) d = ((const int4*)dst)[gi];
    else if (e0 < e) {
      d.x = dst[e0];
      if (e0 + 1 < e) d.y = dst[e0 + 1];
      if (e0 + 2 < e) d.z = dst[e0 + 2];
    }
    if (d.x >= 0) atomicAdd(&h[d.x >> 6], 1);
    if (d.y >= 0) atomicAdd(&h[d.y >> 6], 1);
    if (d.z >= 0) atomicAdd(&h[d.z >> 6], 1);
    if (d.w >= 0) atomicAdd(&h[d.w >> 6], 1);
  }
  __syncthreads();
  for (int i = threadIdx.x; i < nb; i += 256)
    if (h[i]) atomicAdd(&gcount[i], h[i]);
}

// ---------------- exclusive scan of bucket counts (1 block) ----------------
__global__ __launch_bounds__(256) void bucket_scan(const int* __restrict__ gcount,
                                                   int* __restrict__ boff,
                                                   int* __restrict__ gcursor,
                                                   int* __restrict__ row_off,
                                                   int nb, int n) {
  __shared__ int part[256];
  int t = threadIdx.x;
  int v[4];
  int s = 0;
#pragma unroll
  for (int k = 0; k < 4; ++k) {
    int i = t * 4 + k;
    v[k] = (i < nb) ? gcount[i] : 0;
    s += v[k];
  }
  part[t] = s;
  __syncthreads();
  for (int off = 1; off < 256; off <<= 1) {
    int x = part[t];
    if (t >= off) x += part[t - off];
    __syncthreads();
    part[t] = x;
    __syncthreads();
  }
  int run = (t == 0) ? 0 : part[t - 1];
#pragma unroll
  for (int k = 0; k < 4; ++k) {
    int i = t * 4 + k;
    if (i < nb) { boff[i] = run; gcursor[i] = run; }
    run += v[k];
  }
  if (t == 255) { boff[nb] = part[255]; row_off[n] = part[255]; }
}

// ---------------- block-multisplit scatter, int4/float4 loads ----------------
// edge record: meta = (dst&63)<<26 | src ; w as bits
#define EPB 8192
__global__ __launch_bounds__(256) void bucket_scatter(const int* __restrict__ src,
                                                      const int* __restrict__ dst,
                                                      const float* __restrict__ w,
                                                      int* __restrict__ gcursor,
                                                      uint2* __restrict__ ews, int e, int nb) {
  __shared__ int hist[NBMAX];
  __shared__ int gbase[NBMAX];
  __shared__ int lcur[NBMAX];
  const int t = threadIdx.x;
  for (int i = t; i < nb; i += 256) { hist[i] = 0; lcur[i] = 0; }
  __syncthreads();
  const int b4 = blockIdx.x * 2048;  // int4 units; 8192 edges per block
  int4 dv[8];
#pragma unroll
  for (int k = 0; k < 8; ++k) {
    int gi = b4 + k * 256 + t;
    int e0 = gi * 4;
    int4 d = make_int4(-1, -1, -1, -1);
    if (e0 + 3 < e) d = ((const int4*)dst)[gi];
    else if (e0 < e) {
      d.x = dst[e0];
      if (e0 + 1 < e) d.y = dst[e0 + 1];
      if (e0 + 2 < e) d.z = dst[e0 + 2];
    }
    dv[k] = d;
    if (d.x >= 0) atomicAdd(&hist[d.x >> 6], 1);
    if (d.y >= 0) atomicAdd(&hist[d.y >> 6], 1);
    if (d.z >= 0) atomicAdd(&hist[d.z >> 6], 1);
    if (d.w >= 0) atomicAdd(&hist[d.w >> 6], 1);
  }
  __syncthreads();
  for (int i = t; i < nb; i += 256) {
    int c = hist[i];
    gbase[i] = c ? atomicAdd(&gcursor[i], c) : 0;
  }
  __syncthreads();
#pragma unroll
  for (int k = 0; k < 8; ++k) {
    int gi = b4 + k * 256 + t;
    int e0 = gi * 4;
    if (e0 >= e) continue;
    int4 s4 = make_int4(0, 0, 0, 0);
    float4 w4 = make_float4(0.f, 0.f, 0.f, 0.f);
    if (e0 + 3 < e) { s4 = ((const int4*)src)[gi]; w4 = ((const float4*)w)[gi]; }
    else {
      s4.x = src[e0]; w4.x = w[e0];
      if (e0 + 1 < e) { s4.y = src[e0 + 1]; w4.y = w[e0 + 1]; }
      if (e0 + 2 < e) { s4.z = src[e0 + 2]; w4.z = w[e0 + 2]; }
    }
    int4 d = dv[k];
    if (d.x >= 0) { int bb = d.x >> 6; int r = atomicAdd(&lcur[bb], 1);
      ews[gbase[bb] + r] = make_uint2(((unsigned)(d.x & 63) << 26) | (unsigned)s4.x, __float_as_uint(w4.x)); }
    if (d.y >= 0) { int bb = d.y >> 6; int r = atomicAdd(&lcur[bb], 1);
      ews[gbase[bb] + r] = make_uint2(((unsigned)(d.y & 63) << 26) | (unsigned)s4.y, __float_as_uint(w4.y)); }
    if (d.z >= 0) { int bb = d.z >> 6; int r = atomicAdd(&lcur[bb], 1);
      ews[gbase[bb] + r] = make_uint2(((unsigned)(d.z & 63) << 26) | (unsigned)s4.z, __float_as_uint(w4.z)); }
    if (d.w >= 0) { int bb = d.w >> 6; int r = atomicAdd(&lcur[bb], 1);
      ews[gbase[bb] + r] = make_uint2(((unsigned)(d.w & 63) << 26) | (unsigned)s4.w, __float_as_uint(w4.w)); }
  }
}

// ---------------- per-bucket dst-sort: bucket-grouped -> dst-sorted CSR ----------------
__global__ __launch_bounds__(256) void bucket_sort(const uint2* __restrict__ ews,
                                                   const int* __restrict__ boff,
                                                   uint2* __restrict__ ews2,
                                                   int* __restrict__ row_off,
                                                   int n) {
  __shared__ int cnt64[64];
  __shared__ int cur[64];
  const int t = threadIdx.x;
  const int b = blockIdx.x;
  const int e0 = boff[b], e1 = boff[b + 1];
  if (t < 64) cnt64[t] = 0;
  __syncthreads();
  for (int i = e0 + t; i < e1; i += 256) atomicAdd(&cnt64[(unsigned)ews[i].x >> 26], 1);
  __syncthreads();
  if (t == 0) {
    int run = 0;
    for (int d = 0; d < 64; ++d) {
      int c = cnt64[d];
      cur[d] = run;
      run += c;
    }
  }
  __syncthreads();
  if (t < 64) {
    int node = b * 64 + t;
    if (node < n) row_off[node] = e0 + cur[t];
  }
  __syncthreads();
  for (int i = e0 + t; i < e1; i += 256) {
    uint2 p = ews[i];
    int d = (unsigned)p.x >> 26;
    int pos = e0 + atomicAdd(&cur[d], 1);
    ews2[pos] = make_uint2(p.x & 0x3FFFFFFu, p.y);
  }
}

// ---------------- SPMM v4: bf16 gather in round-5's spill-free structure ----------------
// wave/node; lanes 0-31 serve even edge, 32-63 odd edge; each lane gathers
// uint2 = 4 bf16 (8 B) of the 256 B row; fp32 accumulate; shfl_xor(32) merge.
__global__ __launch_bounds__(256) void spmm_bf16(const unsigned short* __restrict__ xin,
                                                 const uint2* __restrict__ ews,
                                                 const int* __restrict__ row_off,
                                                 const float* __restrict__ bias,
                                                 float* __restrict__ outp, int n,
                                                 int do_relu) {
  const int t = threadIdx.x;
  const int l = t & 63;
  const int node = blockIdx.x * 4 + (t >> 6);  // one wave per node
  if (node >= n) return;
  const int ue0 = __builtin_amdgcn_readfirstlane(row_off[node]);
  const int ue1 = __builtin_amdgcn_readfirstlane(row_off[node + 1]);
  const int cnt = ue1 - ue0;
  const uint2* ep = ews + ue0;                 // wave-uniform -> scalar loads
  const int fo = (l & 31) * 4;                 // element offset; 4 bf16 = 8 B per lane
  const int half = l >> 5;                     // 0: even edge, 1: odd edge
  float4 acc = make_float4(0.f, 0.f, 0.f, 0.f);

#define SPMM_PAIR(ea, eb)                                                    \
  {                                                                          \
    unsigned sv = half ? (eb).x : (ea).x;                                    \
    float wt = __uint_as_float(half ? (eb).y : (ea).y);                      \
    const uint2 xv = *(const uint2*)(xin + (size_t)sv * HDIM + fo);          \
    acc.x = fmaf(wt, __uint_as_float(xv.x << 16), acc.x);                    \
    acc.y = fmaf(wt, __uint_as_float(xv.x & 0xFFFF0000u), acc.y);            \
    acc.z = fmaf(wt, __uint_as_float(xv.y << 16), acc.z);                    \
    acc.w = fmaf(wt, __uint_as_float(xv.y & 0xFFFF0000u), acc.w);            \
  }

  int k = 0;
  for (; k + 8 <= cnt; k += 8) {
    uint2 a0 = ep[k + 0], a1 = ep[k + 1], a2 = ep[k + 2], a3 = ep[k + 3];
    uint2 a4 = ep[k + 4], a5 = ep[k + 5], a6 = ep[k + 6], a7 = ep[k + 7];
    SPMM_PAIR(a0, a1);
    SPMM_PAIR(a2, a3);
    SPMM_PAIR(a4, a5);
    SPMM_PAIR(a6, a7);
  }
  for (; k < cnt; k += 2) {
    uint2 a0 = ep[k];
    uint2 a1 = (k + 1 < cnt) ? ep[k + 1] : make_uint2(0u, 0u);
    SPMM_PAIR(a0, a1);
  }
#undef SPMM_PAIR

  acc.x += __shfl_xor(acc.x, 32, 64);
  acc.y += __shfl_xor(acc.y, 32, 64);
  acc.z += __shfl_xor(acc.z, 32, 64);
  acc.w += __shfl_xor(acc.w, 32, 64);
  if (l < 32) {
    float4 bv = *(const float4*)(bias + fo);
    float4 r;
    r.x = acc.x + bv.x;
    r.y = acc.y + bv.y;
    r.z = acc.z + bv.z;
    r.w = acc.w + bv.w;
    if (do_relu) {
      r.x = fmaxf(r.x, 0.f); r.y = fmaxf(r.y, 0.f);
      r.z = fmaxf(r.z, 0.f); r.w = fmaxf(r.w, 0.f);
    }
    *(float4*)(outp + (size_t)node * HDIM + fo) = r;
  }
}

// ---------------- fp32 tiled GEMM, bf16 output: C[M][128] = (scale.A)[M][K] @ W[K][128] ----------------
template <int K, bool SCALE>
__global__ __launch_bounds__(256) void gemm_kernel(const float* __restrict__ A,
                                                   const float* __restrict__ W,
                                                   const float* __restrict__ scale,
                                                   unsigned short* __restrict__ C, int M) {
  __shared__ float AsT[32][64];   // transposed: AsT[k][row] -> b128 fragment reads
  __shared__ float Bs[32][128];
  const int t = threadIdx.x;
  const int tx = t & 15, ty = t >> 4;
  const int m0 = blockIdx.x * 64;
  float acc[4][8];
#pragma unroll
  for (int r = 0; r < 4; ++r)
#pragma unroll
    for (int c = 0; c < 8; ++c) acc[r][c] = 0.f;

  for (int k0 = 0; k0 < K; k0 += 32) {
#pragma unroll
    for (int j = 0; j < 2; ++j) {
      int i = t + j * 256;
      int row = i >> 3, q = i & 7;
      int gr = m0 + row;
      float4 v = make_float4(0.f, 0.f, 0.f, 0.f);
      if (gr < M) {
        v = *(const float4*)(A + (size_t)gr * K + k0 + q * 4);
        if (SCALE) {
          float sc = scale[gr];
          v.x *= sc; v.y *= sc; v.z *= sc; v.w *= sc;
        }
      }
      AsT[q * 4 + 0][row] = v.x;
      AsT[q * 4 + 1][row] = v.y;
      AsT[q * 4 + 2][row] = v.z;
      AsT[q * 4 + 3][row] = v.w;
    }
#pragma unroll
    for (int j = 0; j < 4; ++j) {
      int i = t + j * 256;
      int kr = i >> 5, n4 = i & 31;
      *(float4*)&Bs[kr][n4 * 4] = *(const float4*)(W + (size_t)(k0 + kr) * HDIM + n4 * 4);
    }
    __syncthreads();
#pragma unroll
    for (int kr = 0; kr < 32; ++kr) {
      const float4 a4 = *(const float4*)&AsT[kr][ty * 4];
      float4 b0 = *(const float4*)&Bs[kr][tx * 8];
      float4 b1 = *(const float4*)&Bs[kr][tx * 8 + 4];
      float a[4] = {a4.x, a4.y, a4.z, a4.w};
      float bb[8] = {b0.x, b0.y, b0.z, b0.w, b1.x, b1.y, b1.z, b1.w};
#pragma unroll
      for (int r = 0; r < 4; ++r)
#pragma unroll
        for (int c = 0; c < 8; ++c) acc[r][c] = fmaf(a[r], bb[c], acc[r][c]);
    }
    __syncthreads();
  }
#pragma unroll
  for (int r = 0; r < 4; ++r) {
    int gr = m0 + ty * 4 + r;
    if (gr < M) {
      uint4 o;
      o.x = pkbf(acc[r][0], acc[r][1]);
      o.y = pkbf(acc[r][2], acc[r][3]);
      o.z = pkbf(acc[r][4], acc[r][5]);
      o.w = pkbf(acc[r][6], acc[r][7]);
      *(uint4*)(C + (size_t)gr * HDIM + tx * 8) = o;
    }
  }
}

// ---------------- fold label-emb weights: Wc = We @ Wf_top, bc = be @ Wf_top + bf ----------------
__global__ __launch_bounds__(256) void wc_kernel(const float* __restrict__ We,
                                                 const float* __restrict__ be,
                                                 const float* __restrict__ Wf,
                                                 const float* __restrict__ bf,
                                                 float* __restrict__ Wc,
                                                 float* __restrict__ bc) {
  int t = threadIdx.x;
  for (int i = t; i < CCLS * CCLS; i += 256) {
    int c = i / CCLS, j = i % CCLS;
    float s = 0.f;
    for (int f = 0; f < HDIM; ++f) s += We[c * HDIM + f] * Wf[f * CCLS + j];
    Wc[i] = s;
  }
  if (t < CCLS) {
    float s = bf[t];
    for (int f = 0; f < HDIM; ++f) s += be[f] * Wf[f * CCLS + t];
    bc[t] = s;
  }
}

// ---------------- head v3: lane-per-node, acc[40] in regs, W as LDS broadcasts ----------------
// sW layout: rows 0..39 = Wc (y part), rows 40..167 = Wf[128:256] (h2 part), row 168 = bc.
__global__ __launch_bounds__(64) void head_kernel(const float* __restrict__ y,
                                                  const float* __restrict__ h2,
                                                  const float* __restrict__ Wc,
                                                  const float* __restrict__ bc,
                                                  const float* __restrict__ Wf,
                                                  float* __restrict__ out, int n) {
  __shared__ float sW[169 * CCLS];
  const int t = threadIdx.x;
  for (int i = t; i < 400; i += 64) ((float4*)sW)[i] = ((const float4*)Wc)[i];
  for (int i = t; i < 1280; i += 64)
    ((float4*)(sW + CCLS * CCLS))[i] = ((const float4*)(Wf + HDIM * CCLS))[i];
  if (t < 10) ((float4*)(sW + 168 * CCLS))[t] = ((const float4*)bc)[t];
  __syncthreads();

  const int node = blockIdx.x * 64 + t;
  const int nc = node < n ? node : n - 1;
  const float* zy = y + (size_t)nc * CCLS;
  const float* zh = h2 + (size_t)nc * HDIM;

  float acc[40];
#pragma unroll
  for (int cq = 0; cq < 10; ++cq) {
    float4 b4 = *(const float4*)&sW[168 * CCLS + cq * 4];
    acc[cq * 4 + 0] = b4.x; acc[cq * 4 + 1] = b4.y;
    acc[cq * 4 + 2] = b4.z; acc[cq * 4 + 3] = b4.w;
  }

#pragma unroll 2
  for (int kc = 0; kc < 10; ++kc) {      // y part: K = 40
    float4 zv = *(const float4*)(zy + kc * 4);
    float zj[4] = {zv.x, zv.y, zv.z, zv.w};
#pragma unroll
    for (int j = 0; j < 4; ++j) {
      const float* wr = sW + (kc * 4 + j) * CCLS;
#pragma unroll
      for (int cq = 0; cq < 10; ++cq) {
        float4 w4 = *(const float4*)(wr + cq * 4);
        acc[cq * 4 + 0] = fmaf(zj[j], w4.x, acc[cq * 4 + 0]);
        acc[cq * 4 + 1] = fmaf(zj[j], w4.y, acc[cq * 4 + 1]);
        acc[cq * 4 + 2] = fmaf(zj[j], w4.z, acc[cq * 4 + 2]);
        acc[cq * 4 + 3] = fmaf(zj[j], w4.w, acc[cq * 4 + 3]);
      }
    }
  }
#pragma unroll 2
  for (int kc = 0; kc < 32; ++kc) {      // h2 part: K = 128
    float4 zv = *(const float4*)(zh + kc * 4);
    float zj[4] = {zv.x, zv.y, zv.z, zv.w};
#pragma unroll
    for (int j = 0; j < 4; ++j) {
      const float* wr = sW + (40 + kc * 4 + j) * CCLS;
#pragma unroll
      for (int cq = 0; cq < 10; ++cq) {
        float4 w4 = *(const float4*)(wr + cq * 4);
        acc[cq * 4 + 0] = fmaf(zj[j], w4.x, acc[cq * 4 + 0]);
        acc[cq * 4 + 1] = fmaf(zj[j], w4.y, acc[cq * 4 + 1]);
        acc[cq * 4 + 2] = fmaf(zj[j], w4.z, acc[cq * 4 + 2]);
        acc[cq * 4 + 3] = fmaf(zj[j], w4.w, acc[cq * 4 + 3]);
      }
    }
  }

  // in-register softmax over 40 logits
  float m = acc[0];
#pragma unroll
  for (int c = 1; c < 40; ++c) m = fmaxf(m, acc[c]);
  float sum = 0.f;
#pragma unroll
  for (int c = 0; c < 40; ++c) { acc[c] = __expf(acc[c] - m); sum += acc[c]; }
  float inv = 1.0f / sum;
  if (node < n) {
    float* op = out + (size_t)node * CCLS;
#pragma unroll
    for (int cq = 0; cq < 10; ++cq) {
      float4 o = make_float4(acc[cq * 4 + 0] * inv, acc[cq * 4 + 1] * inv,
                             acc[cq * 4 + 2] * inv, acc[cq * 4 + 3] * inv);
      *(float4*)(op + cq * 4) = o;
    }
  }
}

extern "C" void kernel_launch(void* const* d_in, const int* in_sizes, int n_in,
                              void* d_out, int out_size, void* d_ws, size_t ws_size,
                              hipStream_t stream) {
  (void)n_in; (void)out_size; (void)ws_size;
  const float* features = (const float*)d_in[0];
  const int*   src      = (const int*)d_in[1];
  const int*   dst      = (const int*)d_in[2];
  const float* ew       = (const float*)d_in[3];
  const float* y        = (const float*)d_in[4];
  const float* W1       = (const float*)d_in[5];
  const float* b1       = (const float*)d_in[6];
  const float* W2       = (const float*)d_in[7];
  const float* b2       = (const float*)d_in[8];
  const float* We       = (const float*)d_in[9];
  const float* be       = (const float*)d_in[10];
  const float* Wf       = (const float*)d_in[11];
  const float* bf       = (const float*)d_in[12];
  float* out = (float*)d_out;

  const int n = in_sizes[0] / F_IN;   // 50000
  const int e = in_sizes[1];          // 1600000
  const int nb = (n + 63) >> 6;       // 782 buckets

  char* w = (char*)d_ws;
  auto take = [&](size_t bytes) {
    char* p = w;
    w += (bytes + 255) & ~(size_t)255;
    return p;
  };
  float* inv_norm = (float*)take((size_t)n * 4);
  int*   gcount   = (int*)take((size_t)nb * 4);
  int*   boff     = (int*)take((size_t)(nb + 1) * 4);
  int*   gcursor  = (int*)take((size_t)nb * 4);
  int*   row_off  = (int*)take((size_t)(n + 1) * 4);
  uint2* ews      = (uint2*)take((size_t)e * 8);
  uint2* ews2     = (uint2*)take((size_t)(e + 16) * 8);
  unsigned short* bufH = (unsigned short*)take((size_t)n * HDIM * 2);  // bf16 gemm out
  float* bufS     = (float*)take((size_t)n * HDIM * 4);                 // fp32 spmm out
  float* Wc       = (float*)take(CCLS * CCLS * 4);
  float* bc       = (float*)take(CCLS * 4);

  hipMemsetAsync(gcount, 0, (size_t)nb * 4, stream);
  norm_kernel<<<(n + 3) / 4, 256, 0, stream>>>(features, inv_norm, n);
  bucket_hist<<<(e + 4095) / 4096, 256, 0, stream>>>(dst, gcount, e, nb);
  bucket_scan<<<1, 256, 0, stream>>>(gcount, boff, gcursor, row_off, nb, n);
  bucket_scatter<<<(e + EPB - 1) / EPB, 256, 0, stream>>>(src, dst, ew, gcursor, ews, e, nb);
  bucket_sort<<<nb, 256, 0, stream>>>(ews, boff, ews2, row_off, n);
  wc_kernel<<<1, 256, 0, stream>>>(We, be, Wf, bf, Wc, bc);

  gemm_kernel<F_IN, true><<<(n + 63) / 64, 256, 0, stream>>>(features, W1, inv_norm, bufH, n);
  spmm_bf16<<<(n + 3) / 4, 256, 0, stream>>>(bufH, ews2, row_off, b1, bufS, n, 1);
  gemm_kernel<HDIM, false><<<(n + 63) / 64, 256, 0, stream>>>(bufS, W2, nullptr, bufH, n);
  spmm_bf16<<<(n + 3) / 4, 256, 0, stream>>>(bufH, ews2, row_off, b2, bufS, n, 0);
  head_kernel<<<(n + 63) / 64, 64, 0, stream>>>(y, bufS, Wc, bc, Wf, out, n);
}

// Round 8
// 412.774 us; speedup vs baseline: 2.1235x; 1.0777x over previous
//
#include <hip/hip_runtime.h>
#include <hip/hip_bf16.h>
#include <cstdint>
#include <cstddef>
#include <cmath>

#define F_IN 256
#define HDIM 128
#define CCLS 40
#define NBMAX 1024   // max buckets (n<=65536); n=50000 -> 782

typedef short bf16x8 __attribute__((ext_vector_type(8)));
typedef float f32x4 __attribute__((ext_vector_type(4)));

__device__ inline unsigned pkbf(float a, float b) {
  __hip_bfloat162 h = __float22bfloat162_rn(make_float2(a, b));
  unsigned u;
  __builtin_memcpy(&u, &h, 4);
  return u;
}
__device__ inline unsigned short bfr(float f) {
  __hip_bfloat16 h = __float2bfloat16(f);
  unsigned short u;
  __builtin_memcpy(&u, &h, 2);
  return u;
}

// ---------------- row L2 norm fused with bf16 cast: features -> featbf ----------------
__global__ __launch_bounds__(256) void norm_kernel(const float* __restrict__ x,
                                                   unsigned short* __restrict__ featbf, int n) {
  int wv = threadIdx.x >> 6, l = threadIdx.x & 63;
  int row = blockIdx.x * 4 + wv;
  if (row >= n) return;
  float4 v = *(const float4*)(x + (size_t)row * F_IN + l * 4);
  float s = v.x * v.x + v.y * v.y + v.z * v.z + v.w * v.w;
#pragma unroll
  for (int off = 32; off; off >>= 1) s += __shfl_xor(s, off, 64);
  float inv = 1.0f / fmaxf(sqrtf(s), 1e-12f);
  uint2 o = make_uint2(pkbf(v.x * inv, v.y * inv), pkbf(v.z * inv, v.w * inv));
  *(uint2*)(featbf + (size_t)row * F_IN + l * 4) = o;
}

// ---------------- W transpose + bf16: W1[256][128]->W1T[128][256], W2[128][128]->W2T ----------------
__global__ __launch_bounds__(256) void wt_kernel(const float* __restrict__ W1,
                                                 const float* __restrict__ W2,
                                                 unsigned short* __restrict__ W1T,
                                                 unsigned short* __restrict__ W2T) {
  int idx = blockIdx.x * 256 + threadIdx.x;
  if (idx < 128 * 256) {
    int nr = idx >> 8, k = idx & 255;
    W1T[idx] = bfr(W1[k * 128 + nr]);
  } else {
    int i2 = idx - 128 * 256;
    if (i2 < 128 * 128) {
      int nr = i2 >> 7, k = i2 & 127;
      W2T[i2] = bfr(W2[k * 128 + nr]);
    }
  }
}

// ---------------- bucket histogram (bucket = dst>>6), int4 loads ----------------
__global__ __launch_bounds__(256) void bucket_hist(const int* __restrict__ dst,
                                                   int* __restrict__ gcount, int e, int nb) {
  __shared__ int h[NBMAX];
  for (int i = threadIdx.x; i < nb; i += 256) h[i] = 0;
  __syncthreads();
  int b4 = blockIdx.x * 1024;
#pragma unroll
  for (int k = 0; k < 4; ++k) {
    int gi = b4 + k * 256 + threadIdx.x;
    int e0 = gi * 4;
    int4 d = make_int4(-1, -1, -1, -1);
    if (e0 + 3 < e) d = ((const int4*)dst)[gi];
    else if (e0 < e) {
      d.x = dst[e0];
      if (e0 + 1 < e) d.y = dst[e0 + 1];
      if (e0 + 2 < e) d.z = dst[e0 + 2];
    }
    if (d.x >= 0) atomicAdd(&h[d.x >> 6], 1);
    if (d.y >= 0) atomicAdd(&h[d.y >> 6], 1);
    if (d.z >= 0) atomicAdd(&h[d.z >> 6], 1);
    if (d.w >= 0) atomicAdd(&h[d.w >> 6], 1);
  }
  __syncthreads();
  for (int i = threadIdx.x; i < nb; i += 256)
    if (h[i]) atomicAdd(&gcount[i], h[i]);
}

// ---------------- exclusive scan of bucket counts (1 block) ----------------
__global__ __launch_bounds__(256) void bucket_scan(const int* __restrict__ gcount,
                                                   int* __restrict__ boff,
                                                   int* __restrict__ gcursor,
                                                   int* __restrict__ row_off,
                                                   int nb, int n) {
  __shared__ int part[256];
  int t = threadIdx.x;
  int v[4];
  int s = 0;
#pragma unroll
  for (int k = 0; k < 4; ++k) {
    int i = t * 4 + k;
    v[k] = (i < nb) ? gcount[i] : 0;
    s += v[k];
  }
  part[t] = s;
  __syncthreads();
  for (int off = 1; off < 256; off <<= 1) {
    int x = part[t];
    if (t >= off) x += part[t - off];
    __syncthreads();
    part[t] = x;
    __syncthreads();
  }
  int run = (t == 0) ? 0 : part[t - 1];
#pragma unroll
  for (int k = 0; k < 4; ++k) {
    int i = t * 4 + k;
    if (i < nb) { boff[i] = run; gcursor[i] = run; }
    run += v[k];
  }
  if (t == 255) { boff[nb] = part[255]; row_off[n] = part[255]; }
}

// ---------------- block-multisplit scatter, int4/float4 loads ----------------
#define EPB 8192
__global__ __launch_bounds__(256) void bucket_scatter(const int* __restrict__ src,
                                                      const int* __restrict__ dst,
                                                      const float* __restrict__ w,
                                                      int* __restrict__ gcursor,
                                                      uint2* __restrict__ ews, int e, int nb) {
  __shared__ int hist[NBMAX];
  __shared__ int gbase[NBMAX];
  __shared__ int lcur[NBMAX];
  const int t = threadIdx.x;
  for (int i = t; i < nb; i += 256) { hist[i] = 0; lcur[i] = 0; }
  __syncthreads();
  const int b4 = blockIdx.x * 2048;
  int4 dv[8];
#pragma unroll
  for (int k = 0; k < 8; ++k) {
    int gi = b4 + k * 256 + t;
    int e0 = gi * 4;
    int4 d = make_int4(-1, -1, -1, -1);
    if (e0 + 3 < e) d = ((const int4*)dst)[gi];
    else if (e0 < e) {
      d.x = dst[e0];
      if (e0 + 1 < e) d.y = dst[e0 + 1];
      if (e0 + 2 < e) d.z = dst[e0 + 2];
    }
    dv[k] = d;
    if (d.x >= 0) atomicAdd(&hist[d.x >> 6], 1);
    if (d.y >= 0) atomicAdd(&hist[d.y >> 6], 1);
    if (d.z >= 0) atomicAdd(&hist[d.z >> 6], 1);
    if (d.w >= 0) atomicAdd(&hist[d.w >> 6], 1);
  }
  __syncthreads();
  for (int i = t; i < nb; i += 256) {
    int c = hist[i];
    gbase[i] = c ? atomicAdd(&gcursor[i], c) : 0;
  }
  __syncthreads();
#pragma unroll
  for (int k = 0; k < 8; ++k) {
    int gi = b4 + k * 256 + t;
    int e0 = gi * 4;
    if (e0 >= e) continue;
    int4 s4 = make_int4(0, 0, 0, 0);
    float4 w4 = make_float4(0.f, 0.f, 0.f, 0.f);
    if (e0 + 3 < e) { s4 = ((const int4*)src)[gi]; w4 = ((const float4*)w)[gi]; }
    else {
      s4.x = src[e0]; w4.x = w[e0];
      if (e0 + 1 < e) { s4.y = src[e0 + 1]; w4.y = w[e0 + 1]; }
      if (e0 + 2 < e) { s4.z = src[e0 + 2]; w4.z = w[e0 + 2]; }
    }
    int4 d = dv[k];
    if (d.x >= 0) { int bb = d.x >> 6; int r = atomicAdd(&lcur[bb], 1);
      ews[gbase[bb] + r] = make_uint2(((unsigned)(d.x & 63) << 26) | (unsigned)s4.x, __float_as_uint(w4.x)); }
    if (d.y >= 0) { int bb = d.y >> 6; int r = atomicAdd(&lcur[bb], 1);
      ews[gbase[bb] + r] = make_uint2(((unsigned)(d.y & 63) << 26) | (unsigned)s4.y, __float_as_uint(w4.y)); }
    if (d.z >= 0) { int bb = d.z >> 6; int r = atomicAdd(&lcur[bb], 1);
      ews[gbase[bb] + r] = make_uint2(((unsigned)(d.z & 63) << 26) | (unsigned)s4.z, __float_as_uint(w4.z)); }
    if (d.w >= 0) { int bb = d.w >> 6; int r = atomicAdd(&lcur[bb], 1);
      ews[gbase[bb] + r] = make_uint2(((unsigned)(d.w & 63) << 26) | (unsigned)s4.w, __float_as_uint(w4.w)); }
  }
}

// ---------------- per-bucket dst-sort: bucket-grouped -> dst-sorted CSR ----------------
__global__ __launch_bounds__(256) void bucket_sort(const uint2* __restrict__ ews,
                                                   const int* __restrict__ boff,
                                                   uint2* __restrict__ ews2,
                                                   int* __restrict__ row_off,
                                                   int n) {
  __shared__ int cnt64[64];
  __shared__ int cur[64];
  const int t = threadIdx.x;
  const int b = blockIdx.x;
  const int e0 = boff[b], e1 = boff[b + 1];
  if (t < 64) cnt64[t] = 0;
  __syncthreads();
  for (int i = e0 + t; i < e1; i += 256) atomicAdd(&cnt64[(unsigned)ews[i].x >> 26], 1);
  __syncthreads();
  if (t == 0) {
    int run = 0;
    for (int d = 0; d < 64; ++d) {
      int c = cnt64[d];
      cur[d] = run;
      run += c;
    }
  }
  __syncthreads();
  if (t < 64) {
    int node = b * 64 + t;
    if (node < n) row_off[node] = e0 + cur[t];
  }
  __syncthreads();
  for (int i = e0 + t; i < e1; i += 256) {
    uint2 p = ews[i];
    int d = (unsigned)p.x >> 26;
    int pos = e0 + atomicAdd(&cur[d], 1);
    ews2[pos] = make_uint2(p.x & 0x3FFFFFFu, p.y);
  }
}

// ---------------- SPMM: bf16 gather, wave/node, templated output type ----------------
template <int OUT_BF16>
__global__ __launch_bounds__(256) void spmm_bf16(const unsigned short* __restrict__ xin,
                                                 const uint2* __restrict__ ews,
                                                 const int* __restrict__ row_off,
                                                 const float* __restrict__ bias,
                                                 void* __restrict__ outp, int n,
                                                 int do_relu) {
  const int t = threadIdx.x;
  const int l = t & 63;
  const int node = blockIdx.x * 4 + (t >> 6);  // one wave per node
  if (node >= n) return;
  const int ue0 = __builtin_amdgcn_readfirstlane(row_off[node]);
  const int ue1 = __builtin_amdgcn_readfirstlane(row_off[node + 1]);
  const int cnt = ue1 - ue0;
  const uint2* ep = ews + ue0;                 // wave-uniform -> scalar loads
  const int fo = (l & 31) * 4;                 // element offset; 4 bf16 = 8 B per lane
  const int half = l >> 5;                     // 0: even edge, 1: odd edge
  float4 acc = make_float4(0.f, 0.f, 0.f, 0.f);

#define SPMM_PAIR(ea, eb)                                                    \
  {                                                                          \
    unsigned sv = half ? (eb).x : (ea).x;                                    \
    float wt = __uint_as_float(half ? (eb).y : (ea).y);                      \
    const uint2 xv = *(const uint2*)(xin + (size_t)sv * HDIM + fo);          \
    acc.x = fmaf(wt, __uint_as_float(xv.x << 16), acc.x);                    \
    acc.y = fmaf(wt, __uint_as_float(xv.x & 0xFFFF0000u), acc.y);            \
    acc.z = fmaf(wt, __uint_as_float(xv.y << 16), acc.z);                    \
    acc.w = fmaf(wt, __uint_as_float(xv.y & 0xFFFF0000u), acc.w);            \
  }

  int k = 0;
  for (; k + 8 <= cnt; k += 8) {
    uint2 a0 = ep[k + 0], a1 = ep[k + 1], a2 = ep[k + 2], a3 = ep[k + 3];
    uint2 a4 = ep[k + 4], a5 = ep[k + 5], a6 = ep[k + 6], a7 = ep[k + 7];
    SPMM_PAIR(a0, a1);
    SPMM_PAIR(a2, a3);
    SPMM_PAIR(a4, a5);
    SPMM_PAIR(a6, a7);
  }
  for (; k < cnt; k += 2) {
    uint2 a0 = ep[k];
    uint2 a1 = (k + 1 < cnt) ? ep[k + 1] : make_uint2(0u, 0u);
    SPMM_PAIR(a0, a1);
  }
#undef SPMM_PAIR

  acc.x += __shfl_xor(acc.x, 32, 64);
  acc.y += __shfl_xor(acc.y, 32, 64);
  acc.z += __shfl_xor(acc.z, 32, 64);
  acc.w += __shfl_xor(acc.w, 32, 64);
  if (l < 32) {
    float4 bv = *(const float4*)(bias + fo);
    float4 r;
    r.x = acc.x + bv.x;
    r.y = acc.y + bv.y;
    r.z = acc.z + bv.z;
    r.w = acc.w + bv.w;
    if (do_relu) {
      r.x = fmaxf(r.x, 0.f); r.y = fmaxf(r.y, 0.f);
      r.z = fmaxf(r.z, 0.f); r.w = fmaxf(r.w, 0.f);
    }
    if (OUT_BF16) {
      uint2 o = make_uint2(pkbf(r.x, r.y), pkbf(r.z, r.w));
      *(uint2*)((unsigned short*)outp + (size_t)node * HDIM + fo) = o;
    } else {
      *(float4*)((float*)outp + (size_t)node * HDIM + fo) = r;
    }
  }
}

// ---------------- MFMA GEMM: C[M][128] = A[M][K](bf16) @ W(K x 128, given as WT[128][K] bf16) ----------------
// No LDS, no syncthreads. Wave = 16-row strip; 8 n-tiles of 16; acc 8 x f32x4.
// Verified fragment recipe: A[m=lane&15][k=quad*8+j]; B(k,n): n=lane&15, k=quad*8+j (from WT rows);
// D: col=lane&15, row=quad*4+reg.
template <int K>
__global__ __launch_bounds__(256) void gemm_mfma(const unsigned short* __restrict__ A,
                                                 const unsigned short* __restrict__ WT,
                                                 unsigned short* __restrict__ C, int M) {
  const int t = threadIdx.x;
  const int w = t >> 6, l = t & 63;
  const int ln = l & 15, quad = l >> 4;
  const int m0 = blockIdx.x * 64 + w * 16;
  const int arow = m0 + ln;
  const unsigned short* aptr = A + (size_t)(arow < M ? arow : (M - 1)) * K + quad * 8;

  f32x4 acc[8];
#pragma unroll
  for (int i = 0; i < 8; ++i) acc[i] = (f32x4){0.f, 0.f, 0.f, 0.f};

#pragma unroll
  for (int k0 = 0; k0 < K; k0 += 32) {
    bf16x8 af = *(const bf16x8*)(aptr + k0);
#pragma unroll
    for (int ti = 0; ti < 8; ++ti) {
      bf16x8 bf = *(const bf16x8*)(WT + (size_t)(ti * 16 + ln) * K + k0 + quad * 8);
      acc[ti] = __builtin_amdgcn_mfma_f32_16x16x32_bf16(af, bf, acc[ti], 0, 0, 0);
    }
  }

#pragma unroll
  for (int r = 0; r < 4; ++r) {
    int grow = m0 + quad * 4 + r;
    if (grow < M) {
      unsigned short* cp = C + (size_t)grow * HDIM + ln;
#pragma unroll
      for (int ti = 0; ti < 8; ++ti) cp[ti * 16] = bfr(acc[ti][r]);
    }
  }
}

// ---------------- fold label-emb weights: Wc = We @ Wf_top, bc = be @ Wf_top + bf ----------------
__global__ __launch_bounds__(256) void wc_kernel(const float* __restrict__ We,
                                                 const float* __restrict__ be,
                                                 const float* __restrict__ Wf,
                                                 const float* __restrict__ bf,
                                                 float* __restrict__ Wc,
                                                 float* __restrict__ bc) {
  int t = threadIdx.x;
  for (int i = t; i < CCLS * CCLS; i += 256) {
    int c = i / CCLS, j = i % CCLS;
    float s = 0.f;
    for (int f = 0; f < HDIM; ++f) s += We[c * HDIM + f] * Wf[f * CCLS + j];
    Wc[i] = s;
  }
  if (t < CCLS) {
    float s = bf[t];
    for (int f = 0; f < HDIM; ++f) s += be[f] * Wf[f * CCLS + t];
    bc[t] = s;
  }
}

// ---------------- head v3: lane-per-node, acc[40] in regs, W as LDS broadcasts ----------------
__global__ __launch_bounds__(64) void head_kernel(const float* __restrict__ y,
                                                  const float* __restrict__ h2,
                                                  const float* __restrict__ Wc,
                                                  const float* __restrict__ bc,
                                                  const float* __restrict__ Wf,
                                                  float* __restrict__ out, int n) {
  __shared__ float sW[169 * CCLS];
  const int t = threadIdx.x;
  for (int i = t; i < 400; i += 64) ((float4*)sW)[i] = ((const float4*)Wc)[i];
  for (int i = t; i < 1280; i += 64)
    ((float4*)(sW + CCLS * CCLS))[i] = ((const float4*)(Wf + HDIM * CCLS))[i];
  if (t < 10) ((float4*)(sW + 168 * CCLS))[t] = ((const float4*)bc)[t];
  __syncthreads();

  const int node = blockIdx.x * 64 + t;
  const int nc = node < n ? node : n - 1;
  const float* zy = y + (size_t)nc * CCLS;
  const float* zh = h2 + (size_t)nc * HDIM;

  float acc[40];
#pragma unroll
  for (int cq = 0; cq < 10; ++cq) {
    float4 b4 = *(const float4*)&sW[168 * CCLS + cq * 4];
    acc[cq * 4 + 0] = b4.x; acc[cq * 4 + 1] = b4.y;
    acc[cq * 4 + 2] = b4.z; acc[cq * 4 + 3] = b4.w;
  }

#pragma unroll 2
  for (int kc = 0; kc < 10; ++kc) {      // y part: K = 40
    float4 zv = *(const float4*)(zy + kc * 4);
    float zj[4] = {zv.x, zv.y, zv.z, zv.w};
#pragma unroll
    for (int j = 0; j < 4; ++j) {
      const float* wr = sW + (kc * 4 + j) * CCLS;
#pragma unroll
      for (int cq = 0; cq < 10; ++cq) {
        float4 w4 = *(const float4*)(wr + cq * 4);
        acc[cq * 4 + 0] = fmaf(zj[j], w4.x, acc[cq * 4 + 0]);
        acc[cq * 4 + 1] = fmaf(zj[j], w4.y, acc[cq * 4 + 1]);
        acc[cq * 4 + 2] = fmaf(zj[j], w4.z, acc[cq * 4 + 2]);
        acc[cq * 4 + 3] = fmaf(zj[j], w4.w, acc[cq * 4 + 3]);
      }
    }
  }
#pragma unroll 2
  for (int kc = 0; kc < 32; ++kc) {      // h2 part: K = 128
    float4 zv = *(const float4*)(zh + kc * 4);
    float zj[4] = {zv.x, zv.y, zv.z, zv.w};
#pragma unroll
    for (int j = 0; j < 4; ++j) {
      const float* wr = sW + (40 + kc * 4 + j) * CCLS;
#pragma unroll
      for (int cq = 0; cq < 10; ++cq) {
        float4 w4 = *(const float4*)(wr + cq * 4);
        acc[cq * 4 + 0] = fmaf(zj[j], w4.x, acc[cq * 4 + 0]);
        acc[cq * 4 + 1] = fmaf(zj[j], w4.y, acc[cq * 4 + 1]);
        acc[cq * 4 + 2] = fmaf(zj[j], w4.z, acc[cq * 4 + 2]);
        acc[cq * 4 + 3] = fmaf(zj[j], w4.w, acc[cq * 4 + 3]);
      }
    }
  }

  // in-register softmax over 40 logits
  float m = acc[0];
#pragma unroll
  for (int c = 1; c < 40; ++c) m = fmaxf(m, acc[c]);
  float sum = 0.f;
#pragma unroll
  for (int c = 0; c < 40; ++c) { acc[c] = __expf(acc[c] - m); sum += acc[c]; }
  float inv = 1.0f / sum;
  if (node < n) {
    float* op = out + (size_t)node * CCLS;
#pragma unroll
    for (int cq = 0; cq < 10; ++cq) {
      float4 o = make_float4(acc[cq * 4 + 0] * inv, acc[cq * 4 + 1] * inv,
                             acc[cq * 4 + 2] * inv, acc[cq * 4 + 3] * inv);
      *(float4*)(op + cq * 4) = o;
    }
  }
}

extern "C" void kernel_launch(void* const* d_in, const int* in_sizes, int n_in,
                              void* d_out, int out_size, void* d_ws, size_t ws_size,
                              hipStream_t stream) {
  (void)n_in; (void)out_size; (void)ws_size;
  const float* features = (const float*)d_in[0];
  const int*   src      = (const int*)d_in[1];
  const int*   dst      = (const int*)d_in[2];
  const float* ew       = (const float*)d_in[3];
  const float* y        = (const float*)d_in[4];
  const float* W1       = (const float*)d_in[5];
  const float* b1       = (const float*)d_in[6];
  const float* W2       = (const float*)d_in[7];
  const float* b2       = (const float*)d_in[8];
  const float* We       = (const float*)d_in[9];
  const float* be       = (const float*)d_in[10];
  const float* Wf       = (const float*)d_in[11];
  const float* bf       = (const float*)d_in[12];
  float* out = (float*)d_out;

  const int n = in_sizes[0] / F_IN;   // 50000
  const int e = in_sizes[1];          // 1600000
  const int nb = (n + 63) >> 6;       // 782 buckets

  char* w = (char*)d_ws;
  auto take = [&](size_t bytes) {
    char* p = w;
    w += (bytes + 255) & ~(size_t)255;
    return p;
  };
  int*   gcount   = (int*)take((size_t)nb * 4);
  int*   boff     = (int*)take((size_t)(nb + 1) * 4);
  int*   gcursor  = (int*)take((size_t)nb * 4);
  int*   row_off  = (int*)take((size_t)(n + 1) * 4);
  uint2* ews      = (uint2*)take((size_t)e * 8);
  uint2* ews2     = (uint2*)take((size_t)(e + 16) * 8);
  unsigned short* featbf = (unsigned short*)take((size_t)n * F_IN * 2);  // normalized bf16 features
  unsigned short* bufH1  = (unsigned short*)take((size_t)n * HDIM * 2);  // gemm out (bf16)
  unsigned short* bufH2  = (unsigned short*)take((size_t)n * HDIM * 2);  // spmm1 out (bf16)
  float* bufS     = (float*)take((size_t)n * HDIM * 4);                  // spmm2 out (fp32)
  unsigned short* W1T = (unsigned short*)take((size_t)HDIM * F_IN * 2);
  unsigned short* W2T = (unsigned short*)take((size_t)HDIM * HDIM * 2);
  float* Wc       = (float*)take(CCLS * CCLS * 4);
  float* bc       = (float*)take(CCLS * 4);

  hipMemsetAsync(gcount, 0, (size_t)nb * 4, stream);
  norm_kernel<<<(n + 3) / 4, 256, 0, stream>>>(features, featbf, n);
  bucket_hist<<<(e + 4095) / 4096, 256, 0, stream>>>(dst, gcount, e, nb);
  bucket_scan<<<1, 256, 0, stream>>>(gcount, boff, gcursor, row_off, nb, n);
  bucket_scatter<<<(e + EPB - 1) / EPB, 256, 0, stream>>>(src, dst, ew, gcursor, ews, e, nb);
  bucket_sort<<<nb, 256, 0, stream>>>(ews, boff, ews2, row_off, n);
  wc_kernel<<<1, 256, 0, stream>>>(We, be, Wf, bf, Wc, bc);
  wt_kernel<<<192, 256, 0, stream>>>(W1, W2, W1T, W2T);

  gemm_mfma<F_IN><<<(n + 63) / 64, 256, 0, stream>>>(featbf, W1T, bufH1, n);
  spmm_bf16<1><<<(n + 3) / 4, 256, 0, stream>>>(bufH1, ews2, row_off, b1, bufH2, n, 1);
  gemm_mfma<HDIM><<<(n + 63) / 64, 256, 0, stream>>>(bufH2, W2T, bufH1, n);
  spmm_bf16<0><<<(n + 3) / 4, 256, 0, stream>>>(bufH1, ews2, row_off, b2, bufS, n, 0);
  head_kernel<<<(n + 63) / 64, 64, 0, stream>>>(y, bufS, Wc, bc, Wf, out, n);
}